// Round 3
// baseline (3855.764 us; speedup 1.0000x reference)
//
#include <hip/hip_runtime.h>
#include <cstdint>
#include <cstddef>

#define Bsz 2048
#define Tseq 60
#define Fin 89
#define Hd 1024
#define G4 4096
#define KX 96
#define NOUT 30
#define NBLK 512  // persistent grid: 16 x 32 = 2 blocks/CU on 256 CUs

typedef _Float16 half8 __attribute__((ext_vector_type(8)));
typedef float f32x4 __attribute__((ext_vector_type(4)));

// aux cpol bits (gfx940+): SC0=1, NT=2, SC1=16. SC0|SC1 = device-coherent
// (bypass L1/L2, read the coherent point) -> fresh cross-XCD h reads without
// any cache-invalidate (which would evict L2-resident Upt every step).
template <int AUX>
__device__ __forceinline__ void gload_lds16(const void* g, void* l) {
  __builtin_amdgcn_global_load_lds((const __attribute__((address_space(1))) void*)g,
                                   (__attribute__((address_space(3))) void*)l,
                                   16, 0, AUX);
}

struct CohA   { static constexpr int aux = 0x11; };  // h tiles: coherent
struct CacheA { static constexpr int aux = 0x00; };  // x tiles: cached

__device__ __forceinline__ float sigmoidf_fast(float x) {
  return 1.0f / (1.0f + __expf(-x));
}

// Monotonic grid barrier. Arrival RMW has RELEASE/agent semantics (emits
// buffer_wbl2: flushes this XCD's dirty h-lines to the coherent point).
// Poll is RELAXED (no per-poll invalidate); h freshness comes from the
// SC0|SC1 staging loads. Bounded spin = anti-deadlock safety valve.
__device__ __forceinline__ void grid_barrier(unsigned int* bar,
                                             unsigned int target) {
  __syncthreads();  // all waves' h stores issued (vmcnt drained by barrier)
  if (threadIdx.x == 0) {
    __hip_atomic_fetch_add(bar, 1u, __ATOMIC_RELEASE, __HIP_MEMORY_SCOPE_AGENT);
    unsigned int guard = 0;
    while (__hip_atomic_load(bar, __ATOMIC_RELAXED,
                             __HIP_MEMORY_SCOPE_AGENT) < target) {
      __builtin_amdgcn_s_sleep(1);
      if (++guard > (1u << 22)) break;  // never hang the bench
    }
  }
  __syncthreads();
}

// ---------------------------------------------------------------------------
// Prep kernels (run once per launch; ws is re-poisoned before every call)
// ---------------------------------------------------------------------------

__global__ __launch_bounds__(64) void zero_bar(unsigned int* bar) {
  if (threadIdx.x == 0) *bar = 0u;
}

// x [B][T][Fin] fp32 -> xp [T][B][KX] fp16, zero-padded k in [Fin, KX)
__global__ __launch_bounds__(256) void convert_x(const float* __restrict__ x,
                                                 _Float16* __restrict__ xp) {
  int idx = blockIdx.x * 256 + threadIdx.x;   // < Tseq*Bsz*KX
  int k = idx % KX;
  int b = (idx / KX) % Bsz;
  int t = idx / (KX * Bsz);
  float v = (k < Fin) ? x[((size_t)b * Tseq + t) * Fin + k] : 0.0f;
  xp[idx] = (_Float16)v;
}

// W [Fin][G4] fp32 -> Wpt [G4][KX] fp16 (B^T layout, zero rows k>=Fin)
__global__ __launch_bounds__(256) void transpose_W(const float* __restrict__ W,
                                                   _Float16* __restrict__ Wpt) {
  __shared__ float tile[32][33];
  int n0 = blockIdx.x * 32;
  int k0 = blockIdx.y * 32;
  int tx = threadIdx.x, ty = threadIdx.y;
  for (int i = ty; i < 32; i += 8) {
    int k = k0 + i;
    tile[i][tx] = (k < Fin) ? W[(size_t)k * G4 + n0 + tx] : 0.0f;
  }
  __syncthreads();
  for (int i = ty; i < 32; i += 8)
    Wpt[(size_t)(n0 + i) * KX + k0 + tx] = (_Float16)tile[tx][i];
}

// U [Hd][G4] fp32 -> Upt [G4][Hd] fp16 (B^T layout)
__global__ __launch_bounds__(256) void transpose_U(const float* __restrict__ U,
                                                   _Float16* __restrict__ Upt) {
  __shared__ float tile[32][33];
  int n0 = blockIdx.x * 32;
  int k0 = blockIdx.y * 32;
  int tx = threadIdx.x, ty = threadIdx.y;
  for (int i = ty; i < 32; i += 8)
    tile[i][tx] = U[(size_t)(k0 + i) * G4 + n0 + tx];
  __syncthreads();
  for (int i = ty; i < 32; i += 8)
    Upt[(size_t)(n0 + i) * Hd + k0 + tx] = (_Float16)tile[tx][i];
}

// ---------------------------------------------------------------------------
// Persistent LSTM: all 60 timesteps in one PLAIN-launched kernel.
// Grid = 16 x 32 = 512 blocks; __launch_bounds__(256,2) guarantees
// 2 blocks/CU residency on 256 CUs -> all blocks co-resident -> the custom
// grid barrier is safe. Block (m0/128, j0/32) owns rows m0..+127, hidden
// units j0..+31, all 4 gates, for the whole sequence:
//   - c state in registers (16 floats/lane) for all 60 steps
//   - bias + addressing hoisted out of the time loop
//   - step t's x@W tiles (h-independent) run BEFORE the barrier (absorb skew)
//   - t=0's h@U skipped entirely (h_0 = 0)
//   - h staging loads are SC0|SC1-coherent; h stores flushed by the
//     RELEASE arrival RMW in grid_barrier
// ---------------------------------------------------------------------------
__global__ __launch_bounds__(256, 2) void lstm_persist(
    const _Float16* __restrict__ xp,    // [Tseq][Bsz][KX]
    const _Float16* __restrict__ Wpt,   // [G4][KX]   (B^T)
    const _Float16* __restrict__ Upt,   // [G4][Hd]   (B^T)
    const float*    __restrict__ bias,  // [G4]
    _Float16*       __restrict__ hb0,   // [Bsz][Hd]
    _Float16*       __restrict__ hb1,   // [Bsz][Hd]
    unsigned int*   __restrict__ bar)
{
  __shared__ __align__(16) _Float16 As[128 * 32];  // [row][k]
  __shared__ __align__(16) _Float16 Bs[128 * 32];  // [ln:(gate*32+j)][k]

  const int tid  = threadIdx.x;
  const int wave = tid >> 6;
  const int lane = tid & 63;
  const int quad = lane >> 4;
  const int l16  = lane & 15;
  const int m0 = blockIdx.x * 128;   // batch-row base
  const int j0 = blockIdx.y * 32;    // hidden-unit base

  const int srow  = lane >> 2;        // staging: row within 16-row chunk
  const int skoff = (lane & 3) * 8;   // staging: fp16-element offset in 32-k row

  const int hb    = 16 * (wave & 1);  // hidden sub-base within block
  const int mwave = 64 * (wave >> 1); // row sub-base within block
  const int j = j0 + hb + l16;        // this lane's hidden unit (all 4 gates)

  // hoisted: per-gate bias for this lane's column
  float bv[4];
  for (int p = 0; p < 4; ++p) bv[p] = bias[p * Hd + j];

  // hoisted: B-tile staging global rows (gate-major local layout)
  int bgn[2];
  for (int u = 0; u < 2; ++u) {
    int ln = (wave + 4 * u) * 16 + srow;
    bgn[u] = (ln >> 5) * Hd + j0 + (ln & 31);
  }

  // c state in registers for the whole sequence
  float cr[4][4];
  for (int mi = 0; mi < 4; ++mi)
    for (int r = 0; r < 4; ++r) cr[mi][r] = 0.0f;

  f32x4 acc[4][4];

  // one K-tile: stage A[128][32], B[128][32] via global_load_lds, 16 MFMA
  auto do_tile = [&](const _Float16* Ab, int strA, const _Float16* Bb,
                     int strB, int k0, auto atag) {
    constexpr int AAUX = decltype(atag)::aux;
    __syncthreads();  // previous tile's ds_reads done before overwrite
    {
      int ci = wave;
      gload_lds16<AAUX>(Ab + (size_t)(m0 + ci * 16 + srow) * strA + k0 + skoff,
                        &As[ci * 512]);
      ci = wave + 4;
      gload_lds16<AAUX>(Ab + (size_t)(m0 + ci * 16 + srow) * strA + k0 + skoff,
                        &As[ci * 512]);
      gload_lds16<0>(Bb + (size_t)bgn[0] * strB + k0 + skoff, &Bs[wave * 512]);
      gload_lds16<0>(Bb + (size_t)bgn[1] * strB + k0 + skoff,
                     &Bs[(wave + 4) * 512]);
    }
    __syncthreads();  // drains vmcnt(0): tiles landed

    half8 a[4], bq[4];
    for (int mi = 0; mi < 4; ++mi)
      a[mi] = *(const half8*)&As[(mwave + mi * 16 + l16) * 32 + quad * 8];
    for (int p = 0; p < 4; ++p)
      bq[p] = *(const half8*)&Bs[(p * 32 + hb + l16) * 32 + quad * 8];
    for (int mi = 0; mi < 4; ++mi)
      for (int p = 0; p < 4; ++p)
        acc[mi][p] = __builtin_amdgcn_mfma_f32_16x16x32_f16(a[mi], bq[p],
                                                            acc[mi][p], 0, 0, 0);
  };

  for (int t = 0; t < Tseq; ++t) {
    // init acc with per-gate bias
    for (int mi = 0; mi < 4; ++mi)
      for (int p = 0; p < 4; ++p)
        acc[mi][p] = f32x4{bv[p], bv[p], bv[p], bv[p]};

    // x_t @ W : independent of h -> before the barrier (absorbs skew)
    const _Float16* xp_t = xp + (size_t)t * (Bsz * KX);
    for (int kt = 0; kt < 3; ++kt)
      do_tile(xp_t, KX, Wpt, KX, kt * 32, CacheA{});

    if (t > 0) {
      grid_barrier(bar, (unsigned int)t * NBLK);  // h_{t-1} globally done
      const _Float16* hprev = ((t - 1) & 1) ? hb1 : hb0;
      for (int kt = 0; kt < 32; ++kt)
        do_tile(hprev, Hd, Upt, Hd, kt * 32, CohA{});
    }
    // (t == 0: h_0 = 0, entire h@U contributes nothing -- skipped)

    // gates: lane holds i,f,g,o for hidden unit j, rows quad*4+r (C-layout m89)
    _Float16* hout = (t & 1) ? hb1 : hb0;
    for (int mi = 0; mi < 4; ++mi) {
      for (int r = 0; r < 4; ++r) {
        int row = m0 + mwave + mi * 16 + quad * 4 + r;
        float iv = sigmoidf_fast(acc[mi][0][r]);
        float fv = sigmoidf_fast(acc[mi][1][r]);
        float gv = fmaxf(acc[mi][2][r], 0.0f);   // relu candidate
        float ov = sigmoidf_fast(acc[mi][3][r]);
        float cv = fv * cr[mi][r] + iv * gv;
        cr[mi][r] = cv;
        float hv = ov * fmaxf(cv, 0.0f);         // relu on cell output
        hout[(size_t)row * Hd + j] = (_Float16)hv;
      }
    }
  }
}

// ---------------------------------------------------------------------------
// y[b][o] = bd[o] + sum_k h[b][k] * Wd[k][o]
// ---------------------------------------------------------------------------
__global__ __launch_bounds__(256) void final_dense(const _Float16* __restrict__ h,
                                                   const float* __restrict__ Wd,
                                                   const float* __restrict__ bd,
                                                   float* __restrict__ y) {
  __shared__ float hs[Hd];
  __shared__ float red[8][32];
  int bi = blockIdx.x;
  for (int k = threadIdx.x; k < Hd; k += 256)
    hs[k] = (float)h[(size_t)bi * Hd + k];
  __syncthreads();
  int o  = threadIdx.x & 31;
  int ch = threadIdx.x >> 5;
  float p = 0.0f;
  if (o < NOUT) {
    int k0 = ch * (Hd / 8);
    for (int k = k0; k < k0 + (Hd / 8); ++k)
      p += hs[k] * Wd[(size_t)k * NOUT + o];
  }
  red[ch][o] = p;
  __syncthreads();
  if (threadIdx.x < NOUT) {
    float s = bd[threadIdx.x];
    for (int c2 = 0; c2 < 8; ++c2) s += red[c2][threadIdx.x];
    y[(size_t)bi * NOUT + threadIdx.x] = s;
  }
}

// ---------------------------------------------------------------------------

extern "C" void kernel_launch(void* const* d_in, const int* in_sizes, int n_in,
                              void* d_out, int out_size, void* d_ws, size_t ws_size,
                              hipStream_t stream) {
  const float* x  = (const float*)d_in[0];
  const float* W  = (const float*)d_in[1];
  const float* U  = (const float*)d_in[2];
  const float* b  = (const float*)d_in[3];
  const float* Wd = (const float*)d_in[4];
  const float* bd = (const float*)d_in[5];
  float* y = (float*)d_out;

  char* ws = (char*)d_ws;
  _Float16* xp  = (_Float16*)ws; ws += (size_t)Tseq * Bsz * KX * 2;  // 23.6 MB
  _Float16* Wpt = (_Float16*)ws; ws += (size_t)G4 * KX * 2;          // 0.79 MB
  _Float16* Upt = (_Float16*)ws; ws += (size_t)G4 * Hd * 2;          // 8.4 MB
  _Float16* hb0 = (_Float16*)ws; ws += (size_t)Bsz * Hd * 2;         // 4.2 MB
  _Float16* hb1 = (_Float16*)ws; ws += (size_t)Bsz * Hd * 2;         // 4.2 MB
  unsigned int* bar = (unsigned int*)ws; ws += 256;

  zero_bar<<<1, 64, 0, stream>>>(bar);
  convert_x<<<(Tseq * Bsz * KX) / 256, 256, 0, stream>>>(x, xp);
  transpose_W<<<dim3(G4 / 32, KX / 32), dim3(32, 8), 0, stream>>>(W, Wpt);
  transpose_U<<<dim3(G4 / 32, Hd / 32), dim3(32, 8), 0, stream>>>(U, Upt);

  lstm_persist<<<dim3(16, 32), 256, 0, stream>>>(xp, Wpt, Upt, b, hb0, hb1, bar);

  // h_{59} is in hb1 (59 & 1 == 1)
  final_dense<<<Bsz, 256, 0, stream>>>(hb1, Wd, bd, y);
}

// Round 4
// 1674.177 us; speedup vs baseline: 2.3031x; 2.3031x over previous
//
#include <hip/hip_runtime.h>
#include <cstdint>
#include <cstddef>

#define Bsz 2048
#define Tseq 60
#define Fin 89
#define Hd 1024
#define G4 4096
#define KX 96
#define NOUT 30

typedef _Float16 half8 __attribute__((ext_vector_type(8)));
typedef float f32x4 __attribute__((ext_vector_type(4)));

template <int N> struct IC { static constexpr int value = N; };

__device__ __forceinline__ void gload_lds16(const void* g, void* l) {
  __builtin_amdgcn_global_load_lds((const __attribute__((address_space(1))) void*)g,
                                   (__attribute__((address_space(3))) void*)l,
                                   16, 0, 0);
}

__device__ __forceinline__ float sigmoidf_fast(float x) {
  return 1.0f / (1.0f + __expf(-x));
}

// ---------------------------------------------------------------------------
// Prep kernels (run once per launch; ws is re-poisoned before every call)
// ---------------------------------------------------------------------------

// x [B][T][Fin] fp32 -> xp [T][B][KX] fp16, zero-padded k in [Fin, KX)
__global__ __launch_bounds__(256) void convert_x(const float* __restrict__ x,
                                                 _Float16* __restrict__ xp) {
  int idx = blockIdx.x * 256 + threadIdx.x;   // < Tseq*Bsz*KX
  int k = idx % KX;
  int b = (idx / KX) % Bsz;
  int t = idx / (KX * Bsz);
  float v = (k < Fin) ? x[((size_t)b * Tseq + t) * Fin + k] : 0.0f;
  xp[idx] = (_Float16)v;
}

// W [Fin][G4] fp32 -> Wpt [G4][KX] fp16 (B^T layout, zero rows k>=Fin)
__global__ __launch_bounds__(256) void transpose_W(const float* __restrict__ W,
                                                   _Float16* __restrict__ Wpt) {
  __shared__ float tile[32][33];
  int n0 = blockIdx.x * 32;
  int k0 = blockIdx.y * 32;
  int tx = threadIdx.x, ty = threadIdx.y;
  for (int i = ty; i < 32; i += 8) {
    int k = k0 + i;
    tile[i][tx] = (k < Fin) ? W[(size_t)k * G4 + n0 + tx] : 0.0f;
  }
  __syncthreads();
  for (int i = ty; i < 32; i += 8)
    Wpt[(size_t)(n0 + i) * KX + k0 + tx] = (_Float16)tile[tx][i];
}

// U [Hd][G4] fp32 -> Upt [G4][Hd] fp16 (B^T layout)
__global__ __launch_bounds__(256) void transpose_U(const float* __restrict__ U,
                                                   _Float16* __restrict__ Upt) {
  __shared__ float tile[32][33];
  int n0 = blockIdx.x * 32;
  int k0 = blockIdx.y * 32;
  int tx = threadIdx.x, ty = threadIdx.y;
  for (int i = ty; i < 32; i += 8)
    tile[i][tx] = U[(size_t)(k0 + i) * G4 + n0 + tx];
  __syncthreads();
  for (int i = ty; i < 32; i += 8)
    Upt[(size_t)(n0 + i) * Hd + k0 + tx] = (_Float16)tile[tx][i];
}

// ---------------------------------------------------------------------------
// One LSTM step (launched 60x; kernel boundary gives cross-XCD coherence).
// Block tile: 128 batch rows x [4 gates x 32 hidden units]. Wave w: rows
// 64*(w>>1)..+63, hidden units j0+16*(w&1)..+15, all 4 gates -> each lane
// holds (i,f,g,o) of one hidden unit in registers; epilogue is shuffle-free.
//
// LDS layout (anti-bank-conflict, global_load_lds-compatible):
//   16-row unit = 16 rows x 32 halfs = 1 KB, row-major 64B rows, BUT the four
//   16B chunks of each row are stored XOR-swizzled: slot s of row r holds
//   global chunk s ^ ((r>>1)&3). Staging lane l (row l>>2, slot l&3) therefore
//   reads global chunk (l&3)^((l>>3)&3) -- still 4 lanes per 64B line (dense).
//   Fragment read: lane (quad,l16) wants global chunk `quad` of row l16 ->
//   slot quad^((l16>>1)&3); the wave's 64 reads form a perfect permutation of
//   the 1KB unit -> uniform 2 accesses/bank = conflict-free (m136).
//
// Barriers: x@W staged as ONE 3-subtile round (K=96), h@U as 16 rounds of
// BK=64 -> 34 __syncthreads per step (vs 70 with BK=32).
// ---------------------------------------------------------------------------
__global__ __launch_bounds__(256, 2) void lstm_step(
    const _Float16* __restrict__ xp_t,  // [Bsz][KX]  (this timestep)
    const _Float16* __restrict__ Wpt,   // [G4][KX]   (B^T)
    const _Float16* __restrict__ Upt,   // [G4][Hd]   (B^T)
    const float*    __restrict__ bias,  // [G4]
    const _Float16* __restrict__ h_in,  // [Bsz][Hd]
    _Float16*       __restrict__ h_out, // [Bsz][Hd]
    float*          __restrict__ cst,   // [Bsz][Hd]
    int skip_h)                          // t==0: skip h@U, c_prev = 0
{
  __shared__ __align__(16) _Float16 As[3 * 4096];  // 3 subtiles x 8 units
  __shared__ __align__(16) _Float16 Bs[3 * 4096];

  const int tid  = threadIdx.x;
  const int wave = tid >> 6;
  const int lane = tid & 63;
  const int quad = lane >> 4;
  const int l16  = lane & 15;
  const int m0 = blockIdx.x * 128;   // batch-row base
  const int j0 = blockIdx.y * 32;    // hidden-unit base

  const int srow = lane >> 2;                      // staging row in unit
  const int qg   = (lane & 3) ^ ((lane >> 3) & 3); // staging global chunk
  const int sA   = quad ^ ((l16 >> 1) & 3);        // fragment LDS slot

  const int hb    = 16 * (wave & 1);
  const int mwave = 64 * (wave >> 1);
  const int j  = j0 + hb + l16;
  const int uA = 4 * (wave >> 1);     // A fragment unit base (+mi)
  const int uB = wave & 1;            // B fragment unit base (2p + uB)
  const int aoff = l16 * 32 + sA * 8; // fragment offset within unit (halfs)

  float bv[4];
  for (int p = 0; p < 4; ++p) bv[p] = bias[p * Hd + j];

  f32x4 acc[4][4];
  for (int mi = 0; mi < 4; ++mi)
    for (int p = 0; p < 4; ++p)
      acc[mi][p] = f32x4{bv[p], bv[p], bv[p], bv[p]};

  // stage NC 32-k subtiles of A and B, then 16*NC MFMA
  auto round = [&](auto ncI, const _Float16* __restrict__ Ab, int strA,
                   const _Float16* __restrict__ Bb, int strB, int k0) {
    constexpr int NC = decltype(ncI)::value;
    __syncthreads();  // previous round's ds_reads done before overwrite
#pragma unroll
    for (int ii = 0; ii < NC * 2; ++ii) {
      int i = ii * 4 + wave;        // 0 .. NC*8-1
      int st = i >> 3, ci = i & 7;
      gload_lds16(Ab + (size_t)(m0 + ci * 16 + srow) * strA + k0 + st * 32 + qg * 8,
                  &As[st * 4096 + ci * 512]);
    }
#pragma unroll
    for (int ii = 0; ii < NC * 2; ++ii) {
      int i = ii * 4 + wave;
      int st = i >> 3, ci = i & 7;
      int ln = ci * 16 + srow;
      int gn = (ln >> 5) * Hd + j0 + (ln & 31);   // gate-major B rows
      gload_lds16(Bb + (size_t)gn * strB + k0 + st * 32 + qg * 8,
                  &Bs[st * 4096 + ci * 512]);
    }
    __syncthreads();  // drains vmcnt(0): tiles landed
#pragma unroll
    for (int st = 0; st < NC; ++st) {
      half8 a[4], bq[4];
      for (int mi = 0; mi < 4; ++mi)
        a[mi] = *(const half8*)&As[st * 4096 + (uA + mi) * 512 + aoff];
      for (int p = 0; p < 4; ++p)
        bq[p] = *(const half8*)&Bs[st * 4096 + (2 * p + uB) * 512 + aoff];
      for (int mi = 0; mi < 4; ++mi)
        for (int p = 0; p < 4; ++p)
          acc[mi][p] = __builtin_amdgcn_mfma_f32_16x16x32_f16(a[mi], bq[p],
                                                              acc[mi][p],
                                                              0, 0, 0);
    }
  };

  // x_t @ W : K = 96 = 3 subtiles, one barrier pair
  round(IC<3>{}, xp_t, KX, Wpt, KX, 0);

  // h_{t-1} @ U : 16 rounds of BK=64 (skipped at t=0, h_0 = 0)
  if (!skip_h) {
    for (int r = 0; r < 16; ++r)
      round(IC<2>{}, h_in, Hd, Upt, Hd, r * 64);
  }

  // epilogue: lane holds i,f,g,o for hidden unit j, rows quad*4+r (m89 layout)
  for (int mi = 0; mi < 4; ++mi) {
    for (int r = 0; r < 4; ++r) {
      int row = m0 + mwave + mi * 16 + quad * 4 + r;
      size_t idx = (size_t)row * Hd + j;
      float iv = sigmoidf_fast(acc[mi][0][r]);
      float fv = sigmoidf_fast(acc[mi][1][r]);
      float gv = fmaxf(acc[mi][2][r], 0.0f);   // relu candidate
      float ov = sigmoidf_fast(acc[mi][3][r]);
      float cprev = skip_h ? 0.0f : cst[idx];  // c_0 = 0 folded in
      float cv = fv * cprev + iv * gv;
      cst[idx] = cv;
      float hv = ov * fmaxf(cv, 0.0f);         // relu on cell output
      h_out[idx] = (_Float16)hv;
    }
  }
}

// ---------------------------------------------------------------------------
// y[b][o] = bd[o] + sum_k h[b][k] * Wd[k][o]
// ---------------------------------------------------------------------------
__global__ __launch_bounds__(256) void final_dense(const _Float16* __restrict__ h,
                                                   const float* __restrict__ Wd,
                                                   const float* __restrict__ bd,
                                                   float* __restrict__ y) {
  __shared__ float hs[Hd];
  __shared__ float red[8][32];
  int bi = blockIdx.x;
  for (int k = threadIdx.x; k < Hd; k += 256)
    hs[k] = (float)h[(size_t)bi * Hd + k];
  __syncthreads();
  int o  = threadIdx.x & 31;
  int ch = threadIdx.x >> 5;
  float p = 0.0f;
  if (o < NOUT) {
    int k0 = ch * (Hd / 8);
    for (int k = k0; k < k0 + (Hd / 8); ++k)
      p += hs[k] * Wd[(size_t)k * NOUT + o];
  }
  red[ch][o] = p;
  __syncthreads();
  if (threadIdx.x < NOUT) {
    float s = bd[threadIdx.x];
    for (int c2 = 0; c2 < 8; ++c2) s += red[c2][threadIdx.x];
    y[(size_t)bi * NOUT + threadIdx.x] = s;
  }
}

// ---------------------------------------------------------------------------

extern "C" void kernel_launch(void* const* d_in, const int* in_sizes, int n_in,
                              void* d_out, int out_size, void* d_ws, size_t ws_size,
                              hipStream_t stream) {
  const float* x  = (const float*)d_in[0];
  const float* W  = (const float*)d_in[1];
  const float* U  = (const float*)d_in[2];
  const float* b  = (const float*)d_in[3];
  const float* Wd = (const float*)d_in[4];
  const float* bd = (const float*)d_in[5];
  float* y = (float*)d_out;

  char* ws = (char*)d_ws;
  _Float16* xp  = (_Float16*)ws; ws += (size_t)Tseq * Bsz * KX * 2;  // 23.6 MB
  _Float16* Wpt = (_Float16*)ws; ws += (size_t)G4 * KX * 2;          // 0.79 MB
  _Float16* Upt = (_Float16*)ws; ws += (size_t)G4 * Hd * 2;          // 8.4 MB
  _Float16* hb0 = (_Float16*)ws; ws += (size_t)Bsz * Hd * 2;         // 4.2 MB
  _Float16* hb1 = (_Float16*)ws; ws += (size_t)Bsz * Hd * 2;         // 4.2 MB
  float*    cst = (float*)ws;    ws += (size_t)Bsz * Hd * 4;         // 8.4 MB

  convert_x<<<(Tseq * Bsz * KX) / 256, 256, 0, stream>>>(x, xp);
  transpose_W<<<dim3(G4 / 32, KX / 32), dim3(32, 8), 0, stream>>>(W, Wpt);
  transpose_U<<<dim3(G4 / 32, Hd / 32), dim3(32, 8), 0, stream>>>(U, Upt);

  for (int t = 0; t < Tseq; ++t) {
    const _Float16* hin  = ((t - 1) & 1) ? hb1 : hb0;   // unused at t=0
    _Float16*       hout = (t & 1) ? hb1 : hb0;
    lstm_step<<<dim3(Bsz / 128, G4 / 128), 256, 0, stream>>>(
        xp + (size_t)t * (Bsz * KX), Wpt, Upt, b,
        (t == 0) ? hb0 : hin, hout, cst, (t == 0) ? 1 : 0);
  }

  // h_{59} is in hb1 (59 & 1 == 1)
  final_dense<<<Bsz, 256, 0, stream>>>(hb1, Wd, bd, y);
}